// Round 14
// baseline (239.679 us; speedup 1.0000x reference)
//
#include <hip/hip_runtime.h>

typedef unsigned short u16;
typedef unsigned int u32;
typedef __attribute__((ext_vector_type(8))) short bf16x8;   // 8 bf16 (4 VGPRs)
typedef __attribute__((ext_vector_type(4))) float f32x4;
typedef __attribute__((ext_vector_type(16))) float f32x16;
typedef __attribute__((ext_vector_type(4))) u32 u32x4;

#define S_LEN 2048
#define QKV_N 3072  // 2048 Q + 512 K + 512 V
#define CEXP 0.18033688011f   // 0.125 * log2(e)
#define M32C 5.77078016f      // 32 * CEXP (fixed softmax shift, raw-score units)

__device__ __forceinline__ u16 f2bf(float f) {
  u32 u = __builtin_bit_cast(u32, f);
  u32 r = (u + 0x7FFFu + ((u >> 16) & 1u)) >> 16;  // RNE
  return (u16)r;
}
// one-instruction pack: u32 = bf16(hi)<<16 | bf16(lo), RNE
__device__ __forceinline__ u32 cvtpk(float lo, float hi) {
  u32 r;
  asm("v_cvt_pk_bf16_f32 %0, %1, %2" : "=v"(r) : "v"(lo), "v"(hi));
  return r;
}
__device__ __forceinline__ void gload16(const void* g, void* l) {
  __builtin_amdgcn_global_load_lds(
      (const __attribute__((address_space(1))) u32*)g,
      (__attribute__((address_space(3))) u32*)l, 16, 0, 0);
}

// ---------- fused cast f32 -> bf16 for all 5 inputs, 4 elems/thread ----------
__global__ void cast_all(const float* __restrict__ x, const float* __restrict__ wq,
                         const float* __restrict__ wk, const float* __restrict__ wv,
                         const float* __restrict__ wo, u16* __restrict__ xb,
                         u16* __restrict__ wqkvb, u16* __restrict__ wob) {
  int i = blockIdx.x * 256 + threadIdx.x;
  const float* s;
  u16* d;
  int so, dofs;
  if (i < 2097152) {
    s = x; d = xb; so = i; dofs = i;
  } else if (i < 3145728) {
    s = wq; d = wqkvb; so = i - 2097152; dofs = so;
  } else if (i < 3407872) {
    s = wk; d = wqkvb; so = i - 3145728; dofs = so + 1048576;
  } else if (i < 3670016) {
    s = wv; d = wqkvb; so = i - 3407872; dofs = so + 1310720;
  } else {
    s = wo; d = wob; so = i - 3670016; dofs = so;
  }
  float4 v = ((const float4*)s)[so];
  ((uint2*)d)[dofs] = make_uint2(cvtpk(v.x, v.y), cvtpk(v.z, v.w));
}

// ---------- NT GEMM v5: 128x128 tiles, 8 waves, dbuf, swizzle, 4-phase --------
template <int BM, int BN, int WM, int WN, int OUT_BF16, int ROPE>
__global__ __launch_bounds__(512, 2) void gemm_bt2(const u16* __restrict__ A,
                                                   const u16* __restrict__ B,
                                                   void* __restrict__ Cv,
                                                   int K, int ldc, int nbx,
                                                   const float* __restrict__ fc,
                                                   const float* __restrict__ fs,
                                                   u16* __restrict__ vt) {
  constexpr int MR = BM / WM / 16;
  constexpr int NR = BN / WN / 16;
  constexpr int MR2 = MR / 2, NR2 = NR / 2;
  constexpr int AR = BM / 64, BR = BN / 64;
  __shared__ u16 As0[BM * 64], As1[BM * 64];
  __shared__ u16 Bs0[BN * 64], Bs1[BN * 64];

  const int tid = threadIdx.x;
  const int lane = tid & 63, w = tid >> 6;
  const int wm = w / WN, wn = w % WN;
  const int g = lane >> 4, r16 = lane & 15;
  const int swz = r16 & 7;

  const int nwg = gridDim.x;
  const int q = nwg >> 3, r = nwg & 7;
  const int xcd = blockIdx.x & 7, off = blockIdx.x >> 3;
  const int wg = (xcd < r ? xcd * (q + 1) : r * (q + 1) + (xcd - r) * q) + off;
  const int m0 = (wg / nbx) * BM, n0 = (wg % nbx) * BN;

  const int rowi = tid >> 3;
  const int scol = ((tid & 7) ^ (rowi & 7)) * 8;
  const u16* Ag0 = A + (size_t)(m0 + rowi) * K + scol;
  const u16* Bg0 = B + (size_t)(n0 + rowi) * K + scol;

  f32x4 acc[MR][NR];
#pragma unroll
  for (int mi = 0; mi < MR; ++mi)
#pragma unroll
    for (int ni = 0; ni < NR; ++ni) acc[mi][ni] = f32x4{0.f, 0.f, 0.f, 0.f};

  auto stage = [&](int kb, u16* Ad, u16* Bd) {
#pragma unroll
    for (int rr = 0; rr < AR; ++rr)
      gload16(Ag0 + (size_t)rr * 64 * K + kb, Ad + rr * 4096 + tid * 8);
#pragma unroll
    for (int rr = 0; rr < BR; ++rr)
      gload16(Bg0 + (size_t)rr * 64 * K + kb, Bd + rr * 4096 + tid * 8);
  };

  auto compute = [&](const u16* Asrc, const u16* Bsrc) {
    bf16x8 ac[MR2][2], bc[NR][2];
    const u16* Aw = Asrc + (wm * MR * 16 + r16) * 64;
    const u16* Bw = Bsrc + (wn * NR * 16 + r16) * 64;
#pragma unroll
    for (int mi = 0; mi < MR2; ++mi)
#pragma unroll
      for (int kk = 0; kk < 2; ++kk)
        ac[mi][kk] = *(const bf16x8*)(Aw + mi * 1024 + ((kk * 4 + g) ^ swz) * 8);
#pragma unroll
    for (int ni = 0; ni < NR2; ++ni)
#pragma unroll
      for (int kk = 0; kk < 2; ++kk)
        bc[ni][kk] = *(const bf16x8*)(Bw + ni * 1024 + ((kk * 4 + g) ^ swz) * 8);
    __builtin_amdgcn_s_setprio(1);
#pragma unroll
    for (int mi = 0; mi < MR2; ++mi)
#pragma unroll
      for (int ni = 0; ni < NR2; ++ni)
#pragma unroll
        for (int kk = 0; kk < 2; ++kk)
          acc[mi][ni] = __builtin_amdgcn_mfma_f32_16x16x32_bf16(
              ac[mi][kk], bc[ni][kk], acc[mi][ni], 0, 0, 0);
    __builtin_amdgcn_s_setprio(0);
#pragma unroll
    for (int ni = NR2; ni < NR; ++ni)
#pragma unroll
      for (int kk = 0; kk < 2; ++kk)
        bc[ni][kk] = *(const bf16x8*)(Bw + ni * 1024 + ((kk * 4 + g) ^ swz) * 8);
    __builtin_amdgcn_s_setprio(1);
#pragma unroll
    for (int mi = 0; mi < MR2; ++mi)
#pragma unroll
      for (int ni = NR2; ni < NR; ++ni)
#pragma unroll
        for (int kk = 0; kk < 2; ++kk)
          acc[mi][ni] = __builtin_amdgcn_mfma_f32_16x16x32_bf16(
              ac[mi][kk], bc[ni][kk], acc[mi][ni], 0, 0, 0);
    __builtin_amdgcn_s_setprio(0);
#pragma unroll
    for (int mi = 0; mi < MR2; ++mi)
#pragma unroll
      for (int kk = 0; kk < 2; ++kk)
        ac[mi][kk] =
            *(const bf16x8*)(Aw + (MR2 + mi) * 1024 + ((kk * 4 + g) ^ swz) * 8);
    __builtin_amdgcn_s_setprio(1);
#pragma unroll
    for (int mi = 0; mi < MR2; ++mi)
#pragma unroll
      for (int ni = NR2; ni < NR; ++ni)
#pragma unroll
        for (int kk = 0; kk < 2; ++kk)
          acc[MR2 + mi][ni] = __builtin_amdgcn_mfma_f32_16x16x32_bf16(
              ac[mi][kk], bc[ni][kk], acc[MR2 + mi][ni], 0, 0, 0);
    __builtin_amdgcn_s_setprio(0);
    __builtin_amdgcn_s_setprio(1);
#pragma unroll
    for (int mi = 0; mi < MR2; ++mi)
#pragma unroll
      for (int ni = 0; ni < NR2; ++ni)
#pragma unroll
        for (int kk = 0; kk < 2; ++kk)
          acc[MR2 + mi][ni] = __builtin_amdgcn_mfma_f32_16x16x32_bf16(
              ac[mi][kk], bc[ni][kk], acc[MR2 + mi][ni], 0, 0, 0);
    __builtin_amdgcn_s_setprio(0);
  };

  const int NT = K >> 6;
  stage(0, As0, Bs0);
  __syncthreads();
  for (int t = 0; t < NT; t += 2) {
    if (t + 1 < NT) stage((t + 1) * 64, As1, Bs1);
    compute(As0, Bs0);
    __syncthreads();
    if (t + 2 < NT) stage((t + 2) * 64, As0, Bs0);
    compute(As1, Bs1);
    __syncthreads();
  }

  if (ROPE && n0 >= 2560) {
#pragma unroll
    for (int mi = 0; mi < MR; ++mi)
#pragma unroll
      for (int ni = 0; ni < NR; ++ni) {
        int row = m0 + wm * MR * 16 + mi * 16 + g * 4;
        int col = n0 + wn * NR * 16 + ni * 16 + r16;
        int kv = (col - 2560) >> 6;
        int d = (col - 2560) & 63;
        int b_ = row >> 11, s0 = row & 2047;
        *(uint2*)&vt[(size_t)((b_ * 8 + kv) * 64 + d) * 2048 + s0] =
            make_uint2(cvtpk(acc[mi][ni][0], acc[mi][ni][1]),
                       cvtpk(acc[mi][ni][2], acc[mi][ni][3]));
      }
    return;
  }

#pragma unroll
  for (int mi = 0; mi < MR; ++mi)
#pragma unroll
    for (int ni = 0; ni < NR; ++ni) {
      int row = m0 + wm * MR * 16 + mi * 16 + g * 4;
      int col = n0 + wn * NR * 16 + ni * 16 + r16;
#pragma unroll
      for (int j = 0; j < 4; ++j) {
        float v = acc[mi][ni][j];
        if (ROPE) {
          float pv = __shfl_xor(v, 1);  // partner column of the RoPE pair
          int s = (row + j) & (S_LEN - 1);
          int fi = (col >> 1) & 31;
          float c = fc[s * 32 + fi], sn = fs[s * 32 + fi];
          v = fmaf(pv, (r16 & 1) ? sn : -sn, v * c);
        }
        if (OUT_BF16)
          ((u16*)Cv)[(size_t)(row + j) * ldc + col] = f2bf(v);
        else
          ((float*)Cv)[(size_t)(row + j) * ldc + col] = v;
      }
    }
}

// ---------- flash attention v10: no LDS, no barriers, direct-L2 K/V ----------
// grid (bh=64, y=16); 4 independent waves/block, 32 q/wave, per-wave causal
// loop bound. 32x32 swapped QK^T, in-register softmax (layout verified R13).
__global__ __launch_bounds__(256, 3) void attn_fwd(const u16* __restrict__ qkv,
                                                   const u16* __restrict__ vt,
                                                   u16* __restrict__ aout) {
  const int bh = blockIdx.x;
  const int y = blockIdx.y;
  const int qt = (y < 4) ? (15 - y) : (y < 8) ? (y - 4) : (y < 12) ? y : (19 - y);
  const int b = bh >> 5, h = bh & 31, kvh = h >> 2;
  const int tid = threadIdx.x;
  const int w = tid >> 6, lane = tid & 63;
  const int l31 = lane & 31, hi = lane >> 5;
  const int q0w = qt * 128 + w * 32;

  const u16* kbase = qkv + (size_t)b * S_LEN * QKV_N + 2048 + kvh * 64;
  const u16* vbase = vt + (size_t)(b * 8 + kvh) * 64 * S_LEN;

  // Q fragments (B operand): lane l holds Q[q0w + l31][ds*16 + hi*8 + 0..7]
  bf16x8 qf[4];
  {
    const u16* qrow = qkv + (size_t)(b * S_LEN + q0w + l31) * QKV_N + h * 64;
#pragma unroll
    for (int ds = 0; ds < 4; ++ds)
      qf[ds] = *(const bf16x8*)(qrow + ds * 16 + hi * 8);
  }

  f32x16 oacc[2];
#pragma unroll
  for (int i = 0; i < 16; ++i) {
    oacc[0][i] = 0.f;
    oacc[1][i] = 0.f;
  }
  float lsum = 0.f;

  const int ntw = ((q0w + 31) >> 6) + 1;  // this wave's causal tile count

  const u16* krow0 = kbase + (size_t)l31 * QKV_N + hi * 8;
  const u16* vrow0 = vbase + (size_t)l31 * 2048 + hi * 8;

  for (int t = 0; t < ntw; ++t) {
    const int k0 = t * 64;
    const bool needmask = (k0 + 63 > q0w);
#pragma unroll
    for (int kt = 0; kt < 2; ++kt) {
      // A-frag of K (direct from L2): K[k0 + kt*32 + l31][ds*16 + hi*8 ..]
      const u16* krow = krow0 + (size_t)(k0 + kt * 32) * QKV_N;
      bf16x8 kfA[4];
#pragma unroll
      for (int ds = 0; ds < 4; ++ds)
        kfA[ds] = *(const bf16x8*)(krow + ds * 16);
      f32x16 s;
#pragma unroll
      for (int i = 0; i < 16; ++i) s[i] = 0.f;
      __builtin_amdgcn_s_setprio(1);
#pragma unroll
      for (int ds = 0; ds < 4; ++ds)
        s = __builtin_amdgcn_mfma_f32_32x32x16_bf16(kfA[ds], qf[ds], s, 0, 0, 0);
      __builtin_amdgcn_s_setprio(0);
      // C layout: col q = l31; row k' = (r&3) + 8*(r>>2) + 4*hi
      if (needmask) {
        const int qg = q0w + l31;
        const int kb0 = k0 + kt * 32 + 4 * hi;
#pragma unroll
        for (int r = 0; r < 16; ++r)
          if (kb0 + (r & 3) + 8 * (r >> 2) > qg) s[r] = -__builtin_inff();
      }
      // fixed-shift softmax, lane-local (lane owns one q)
      float p[16];
      float ps = 0.f;
#pragma unroll
      for (int r = 0; r < 16; ++r) {
        p[r] = exp2f(fmaf(s[r], CEXP, -M32C));
        ps += p[r];
      }
      lsum += ps;
      // pack P into PV A-fragments: own/partner half exchange via shfl_xor(32)
#pragma unroll
      for (int ks = 0; ks < 2; ++ks) {
        u32 wA = cvtpk(p[8 * ks + 0], p[8 * ks + 1]);
        u32 wB = cvtpk(p[8 * ks + 2], p[8 * ks + 3]);
        u32 wC = cvtpk(p[8 * ks + 4], p[8 * ks + 5]);
        u32 wD = cvtpk(p[8 * ks + 6], p[8 * ks + 7]);
        u32 xA = __shfl_xor(wA, 32);
        u32 xB = __shfl_xor(wB, 32);
        u32 xC = __shfl_xor(wC, 32);
        u32 xD = __shfl_xor(wD, 32);
        u32x4 w4;
        w4[0] = hi ? xC : wA;
        w4[1] = hi ? xD : wB;
        w4[2] = hi ? wC : xA;
        w4[3] = hi ? wD : xB;
        bf16x8 pa = __builtin_bit_cast(bf16x8, w4);
        __builtin_amdgcn_s_setprio(1);
#pragma unroll
        for (int dt = 0; dt < 2; ++dt) {
          // V fragment direct from L2: vt row d = dt*32+l31, cols k0+kt*32+ks*16+hi*8
          bf16x8 vf = *(const bf16x8*)(vrow0 + (size_t)(dt * 32) * 2048 + k0 +
                                       kt * 32 + ks * 16);
          oacc[dt] =
              __builtin_amdgcn_mfma_f32_32x32x16_bf16(pa, vf, oacc[dt], 0, 0, 0);
        }
        __builtin_amdgcn_s_setprio(0);
      }
    }
  }

  // epilogue: combine k-halves of lsum, broadcast inverse to output rows
  float lt = lsum + __shfl_xor(lsum, 32);
  float inv = 1.f / lt;
  float ivr[16];
#pragma unroll
  for (int r = 0; r < 16; ++r)
    ivr[r] = __shfl(inv, (r & 3) + 8 * (r >> 2) + 4 * hi);
#pragma unroll
  for (int dt = 0; dt < 2; ++dt)
#pragma unroll
    for (int r = 0; r < 16; ++r) {
      int qrow = q0w + (r & 3) + 8 * (r >> 2) + 4 * hi;
      size_t o = (size_t)(b * S_LEN + qrow) * 2048 + h * 64 + dt * 32 + l31;
      aout[o] = f2bf(oacc[dt][r] * ivr[r]);
    }
}

extern "C" void kernel_launch(void* const* d_in, const int* in_sizes, int n_in,
                              void* d_out, int out_size, void* d_ws,
                              size_t ws_size, hipStream_t stream) {
  const float* x = (const float*)d_in[0];
  const float* fc = (const float*)d_in[1];
  const float* fs = (const float*)d_in[2];
  const float* wq = (const float*)d_in[3];
  const float* wk = (const float*)d_in[4];
  const float* wv = (const float*)d_in[5];
  const float* wo = (const float*)d_in[6];
  float* out = (float*)d_out;

  char* ws = (char*)d_ws;
  u16* xb = (u16*)(ws);
  u16* wqkvb = (u16*)(ws + 16777216);
  u16* wob = (u16*)(ws + 29360128);
  u16* qkvb = (u16*)(ws + 37748736);
  u16* vtb = (u16*)(ws + 62914560);
  u16* aoutb = (u16*)(ws + 67108864);

  cast_all<<<18432, 256, 0, stream>>>(x, wq, wk, wv, wo, xb, wqkvb, wob);

  // QKV = xb * wqkv^T with fused RoPE (Q,K tiles) + fused V-transpose (V tiles)
  gemm_bt2<128, 128, 2, 4, 1, 1><<<768, 512, 0, stream>>>(
      xb, wqkvb, qkvb, 2048, 3072, 24, fc, fs, vtb);
  attn_fwd<<<dim3(64, 16), 256, 0, stream>>>(qkvb, vtb, aoutb);
  gemm_bt2<128, 128, 2, 4, 0, 0><<<512, 512, 0, stream>>>(
      aoutb, wob, out, 2048, 2048, 16, nullptr, nullptr, nullptr);
}

// Round 15
// 191.201 us; speedup vs baseline: 1.2535x; 1.2535x over previous
//
#include <hip/hip_runtime.h>

typedef unsigned short u16;
typedef unsigned int u32;
typedef __attribute__((ext_vector_type(8))) short bf16x8;  // 8 bf16 (4 VGPRs)
typedef __attribute__((ext_vector_type(4))) float f32x4;

#define S_LEN 2048
#define QKV_N 3072  // 2048 Q + 512 K + 512 V
#define CEXP 0.18033688011f   // 0.125 * log2(e)
#define M32C 5.77078016f      // 32 * CEXP (fixed softmax shift, raw-score units)

__device__ __forceinline__ u16 f2bf(float f) {
  u32 u = __builtin_bit_cast(u32, f);
  u32 r = (u + 0x7FFFu + ((u >> 16) & 1u)) >> 16;  // RNE
  return (u16)r;
}
// one-instruction pack: u32 = bf16(hi)<<16 | bf16(lo), RNE
__device__ __forceinline__ u32 cvtpk(float lo, float hi) {
  u32 r;
  asm("v_cvt_pk_bf16_f32 %0, %1, %2" : "=v"(r) : "v"(lo), "v"(hi));
  return r;
}
__device__ __forceinline__ void gload16(const void* g, void* l) {
  __builtin_amdgcn_global_load_lds(
      (const __attribute__((address_space(1))) u32*)g,
      (__attribute__((address_space(3))) u32*)l, 16, 0, 0);
}

// ---------- fused cast f32 -> bf16 for all 5 inputs, 4 elems/thread ----------
__global__ void cast_all(const float* __restrict__ x, const float* __restrict__ wq,
                         const float* __restrict__ wk, const float* __restrict__ wv,
                         const float* __restrict__ wo, u16* __restrict__ xb,
                         u16* __restrict__ wqkvb, u16* __restrict__ wob) {
  int i = blockIdx.x * 256 + threadIdx.x;
  const float* s;
  u16* d;
  int so, dofs;
  if (i < 2097152) {
    s = x; d = xb; so = i; dofs = i;
  } else if (i < 3145728) {
    s = wq; d = wqkvb; so = i - 2097152; dofs = so;
  } else if (i < 3407872) {
    s = wk; d = wqkvb; so = i - 3145728; dofs = so + 1048576;
  } else if (i < 3670016) {
    s = wv; d = wqkvb; so = i - 3407872; dofs = so + 1310720;
  } else {
    s = wo; d = wob; so = i - 3670016; dofs = so;
  }
  float4 v = ((const float4*)s)[so];
  ((uint2*)d)[dofs] = make_uint2(cvtpk(v.x, v.y), cvtpk(v.z, v.w));
}

// ---------- NT GEMM v5: 128x128 tiles, 8 waves, dbuf, swizzle, 4-phase --------
template <int BM, int BN, int WM, int WN, int OUT_BF16, int ROPE>
__global__ __launch_bounds__(512, 2) void gemm_bt2(const u16* __restrict__ A,
                                                   const u16* __restrict__ B,
                                                   void* __restrict__ Cv,
                                                   int K, int ldc, int nbx,
                                                   const float* __restrict__ fc,
                                                   const float* __restrict__ fs,
                                                   u16* __restrict__ vt) {
  constexpr int MR = BM / WM / 16;
  constexpr int NR = BN / WN / 16;
  constexpr int MR2 = MR / 2, NR2 = NR / 2;
  constexpr int AR = BM / 64, BR = BN / 64;
  __shared__ u16 As0[BM * 64], As1[BM * 64];
  __shared__ u16 Bs0[BN * 64], Bs1[BN * 64];

  const int tid = threadIdx.x;
  const int lane = tid & 63, w = tid >> 6;
  const int wm = w / WN, wn = w % WN;
  const int g = lane >> 4, r16 = lane & 15;
  const int swz = r16 & 7;

  const int nwg = gridDim.x;
  const int q = nwg >> 3, r = nwg & 7;
  const int xcd = blockIdx.x & 7, off = blockIdx.x >> 3;
  const int wg = (xcd < r ? xcd * (q + 1) : r * (q + 1) + (xcd - r) * q) + off;
  const int m0 = (wg / nbx) * BM, n0 = (wg % nbx) * BN;

  const int rowi = tid >> 3;
  const int scol = ((tid & 7) ^ (rowi & 7)) * 8;
  const u16* Ag0 = A + (size_t)(m0 + rowi) * K + scol;
  const u16* Bg0 = B + (size_t)(n0 + rowi) * K + scol;

  f32x4 acc[MR][NR];
#pragma unroll
  for (int mi = 0; mi < MR; ++mi)
#pragma unroll
    for (int ni = 0; ni < NR; ++ni) acc[mi][ni] = f32x4{0.f, 0.f, 0.f, 0.f};

  auto stage = [&](int kb, u16* Ad, u16* Bd) {
#pragma unroll
    for (int rr = 0; rr < AR; ++rr)
      gload16(Ag0 + (size_t)rr * 64 * K + kb, Ad + rr * 4096 + tid * 8);
#pragma unroll
    for (int rr = 0; rr < BR; ++rr)
      gload16(Bg0 + (size_t)rr * 64 * K + kb, Bd + rr * 4096 + tid * 8);
  };

  auto compute = [&](const u16* Asrc, const u16* Bsrc) {
    bf16x8 ac[MR2][2], bc[NR][2];
    const u16* Aw = Asrc + (wm * MR * 16 + r16) * 64;
    const u16* Bw = Bsrc + (wn * NR * 16 + r16) * 64;
#pragma unroll
    for (int mi = 0; mi < MR2; ++mi)
#pragma unroll
      for (int kk = 0; kk < 2; ++kk)
        ac[mi][kk] = *(const bf16x8*)(Aw + mi * 1024 + ((kk * 4 + g) ^ swz) * 8);
#pragma unroll
    for (int ni = 0; ni < NR2; ++ni)
#pragma unroll
      for (int kk = 0; kk < 2; ++kk)
        bc[ni][kk] = *(const bf16x8*)(Bw + ni * 1024 + ((kk * 4 + g) ^ swz) * 8);
    __builtin_amdgcn_s_setprio(1);
#pragma unroll
    for (int mi = 0; mi < MR2; ++mi)
#pragma unroll
      for (int ni = 0; ni < NR2; ++ni)
#pragma unroll
        for (int kk = 0; kk < 2; ++kk)
          acc[mi][ni] = __builtin_amdgcn_mfma_f32_16x16x32_bf16(
              ac[mi][kk], bc[ni][kk], acc[mi][ni], 0, 0, 0);
    __builtin_amdgcn_s_setprio(0);
#pragma unroll
    for (int ni = NR2; ni < NR; ++ni)
#pragma unroll
      for (int kk = 0; kk < 2; ++kk)
        bc[ni][kk] = *(const bf16x8*)(Bw + ni * 1024 + ((kk * 4 + g) ^ swz) * 8);
    __builtin_amdgcn_s_setprio(1);
#pragma unroll
    for (int mi = 0; mi < MR2; ++mi)
#pragma unroll
      for (int ni = NR2; ni < NR; ++ni)
#pragma unroll
        for (int kk = 0; kk < 2; ++kk)
          acc[mi][ni] = __builtin_amdgcn_mfma_f32_16x16x32_bf16(
              ac[mi][kk], bc[ni][kk], acc[mi][ni], 0, 0, 0);
    __builtin_amdgcn_s_setprio(0);
#pragma unroll
    for (int mi = 0; mi < MR2; ++mi)
#pragma unroll
      for (int kk = 0; kk < 2; ++kk)
        ac[mi][kk] =
            *(const bf16x8*)(Aw + (MR2 + mi) * 1024 + ((kk * 4 + g) ^ swz) * 8);
    __builtin_amdgcn_s_setprio(1);
#pragma unroll
    for (int mi = 0; mi < MR2; ++mi)
#pragma unroll
      for (int ni = NR2; ni < NR; ++ni)
#pragma unroll
        for (int kk = 0; kk < 2; ++kk)
          acc[MR2 + mi][ni] = __builtin_amdgcn_mfma_f32_16x16x32_bf16(
              ac[mi][kk], bc[ni][kk], acc[MR2 + mi][ni], 0, 0, 0);
    __builtin_amdgcn_s_setprio(0);
    __builtin_amdgcn_s_setprio(1);
#pragma unroll
    for (int mi = 0; mi < MR2; ++mi)
#pragma unroll
      for (int ni = 0; ni < NR2; ++ni)
#pragma unroll
        for (int kk = 0; kk < 2; ++kk)
          acc[MR2 + mi][ni] = __builtin_amdgcn_mfma_f32_16x16x32_bf16(
              ac[mi][kk], bc[ni][kk], acc[MR2 + mi][ni], 0, 0, 0);
    __builtin_amdgcn_s_setprio(0);
  };

  const int NT = K >> 6;
  stage(0, As0, Bs0);
  __syncthreads();
  for (int t = 0; t < NT; t += 2) {
    if (t + 1 < NT) stage((t + 1) * 64, As1, Bs1);
    compute(As0, Bs0);
    __syncthreads();
    if (t + 2 < NT) stage((t + 2) * 64, As0, Bs0);
    compute(As1, Bs1);
    __syncthreads();
  }

  if (ROPE && n0 >= 2560) {
#pragma unroll
    for (int mi = 0; mi < MR; ++mi)
#pragma unroll
      for (int ni = 0; ni < NR; ++ni) {
        int row = m0 + wm * MR * 16 + mi * 16 + g * 4;
        int col = n0 + wn * NR * 16 + ni * 16 + r16;
        int kv = (col - 2560) >> 6;
        int d = (col - 2560) & 63;
        int b_ = row >> 11, s0 = row & 2047;
        *(uint2*)&vt[(size_t)((b_ * 8 + kv) * 64 + d) * 2048 + s0] =
            make_uint2(cvtpk(acc[mi][ni][0], acc[mi][ni][1]),
                       cvtpk(acc[mi][ni][2], acc[mi][ni][3]));
      }
    return;
  }

#pragma unroll
  for (int mi = 0; mi < MR; ++mi)
#pragma unroll
    for (int ni = 0; ni < NR; ++ni) {
      int row = m0 + wm * MR * 16 + mi * 16 + g * 4;
      int col = n0 + wn * NR * 16 + ni * 16 + r16;
#pragma unroll
      for (int j = 0; j < 4; ++j) {
        float v = acc[mi][ni][j];
        if (ROPE) {
          float pv = __shfl_xor(v, 1);  // partner column of the RoPE pair
          int s = (row + j) & (S_LEN - 1);
          int fi = (col >> 1) & 31;
          float c = fc[s * 32 + fi], sn = fs[s * 32 + fi];
          v = fmaf(pv, (r16 & 1) ? sn : -sn, v * c);
        }
        if (OUT_BF16)
          ((u16*)Cv)[(size_t)(row + j) * ldc + col] = f2bf(v);
        else
          ((float*)Cv)[(size_t)(row + j) * ldc + col] = v;
      }
    }
}

// ---------- flash attention v11: 8-wave blocks (QBLK=256), shared KV stream ---
// grid (bh=64, y=8); 8 waves/block, 32 q/wave, KVBLK=64, dbuf LDS (48KB).
// qt perm P=[7,6,5,4,0,1,2,3]: CU pairs (y, y+4) sum to 36 iterations exactly.
// Per-wave compute core identical to the R12 known-good 16x16 version.
__global__ __launch_bounds__(512, 2) void attn_fwd(const u16* __restrict__ qkv,
                                                   const u16* __restrict__ vt,
                                                   u16* __restrict__ aout) {
  __shared__ u16 Ks[2][64 * 64];
  __shared__ u16 Vs[2][64 * 64];
  __shared__ u16 Ps[8][16 * 64];  // per-wave P tile

  const int bh = blockIdx.x;
  const int y = blockIdx.y;
  const int qt = (y < 4) ? (7 - y) : (y - 4);
  const int b = bh >> 5, h = bh & 31, kvh = h >> 2;
  const int tid = threadIdx.x;
  const int w = tid >> 6, lane = tid & 63;
  const int g = lane >> 4, r16 = lane & 15;
  const int q0w = qt * 256 + w * 32;

  const u16* kbase = qkv + (size_t)b * S_LEN * QKV_N + 2048 + kvh * 64;
  const u16* vbase = vt + (size_t)(b * 8 + kvh) * 64 * S_LEN;

  // staging: 512 threads x 16B = 8KB = one 64x64 bf16 tile per operand
  const int rowi = tid >> 3;                        // 0..63
  const int scol = ((tid & 7) ^ (rowi & 7)) * 8;    // pre-swizzled source col
  const int swz = (r16 & 7) * 8;                    // read-side XOR (u16)

  bf16x8 qf[2][2];
#pragma unroll
  for (int qs = 0; qs < 2; ++qs) {
    const u16* qrow =
        qkv + (size_t)(b * S_LEN + q0w + qs * 16 + r16) * QKV_N + h * 64;
#pragma unroll
    for (int dh = 0; dh < 2; ++dh)
      qf[qs][dh] = *(const bf16x8*)(qrow + dh * 32 + g * 8);
  }

  f32x4 oacc[2][4];
#pragma unroll
  for (int qs = 0; qs < 2; ++qs)
#pragma unroll
    for (int dt = 0; dt < 4; ++dt) oacc[qs][dt] = f32x4{0.f, 0.f, 0.f, 0.f};
  float lsum[2] = {0.f, 0.f};

  const int nt = qt * 4 + 4;               // block k-tiles (64 keys each)
  const int ntw = ((q0w + 31) >> 6) + 1;   // this wave's causal tile count

  gload16(kbase + (size_t)rowi * QKV_N + scol, &Ks[0][tid * 8]);
  gload16(vbase + (size_t)rowi * 2048 + scol, &Vs[0][tid * 8]);
  __syncthreads();

  int cur = 0;
  for (int t = 0; t < nt; ++t) {
    if (t + 1 < nt) {
      int kk0 = (t + 1) * 64;
      gload16(kbase + (size_t)(kk0 + rowi) * QKV_N + scol, &Ks[cur ^ 1][tid * 8]);
      gload16(vbase + (size_t)rowi * 2048 + kk0 + scol, &Vs[cur ^ 1][tid * 8]);
    }
    if (t < ntw) {
      const int k0 = t * 64;
      bf16x8 kf[4][2];
#pragma unroll
      for (int ks = 0; ks < 4; ++ks)
#pragma unroll
        for (int dh = 0; dh < 2; ++dh)
          kf[ks][dh] = *(const bf16x8*)&Ks[cur][(ks * 16 + r16) * 64 +
                                               ((dh * 32 + g * 8) ^ swz)];
      bf16x8 vfc[2][4];  // V fragments cached in regs, shared across qs
#pragma unroll
      for (int ks2 = 0; ks2 < 2; ++ks2)
#pragma unroll
        for (int dt = 0; dt < 4; ++dt)
          vfc[ks2][dt] = *(const bf16x8*)&Vs[cur][(dt * 16 + r16) * 64 +
                                                  ((ks2 * 32 + g * 8) ^ swz)];
      const bool needmask = (k0 + 63 > q0w);
#pragma unroll
      for (int qs = 0; qs < 2; ++qs) {
        f32x4 st[4];
        __builtin_amdgcn_s_setprio(1);
#pragma unroll
        for (int ks = 0; ks < 4; ++ks) {
          f32x4 a = f32x4{0.f, 0.f, 0.f, 0.f};
          a = __builtin_amdgcn_mfma_f32_16x16x32_bf16(kf[ks][0], qf[qs][0], a, 0, 0, 0);
          a = __builtin_amdgcn_mfma_f32_16x16x32_bf16(kf[ks][1], qf[qs][1], a, 0, 0, 0);
          st[ks] = a;  // row k'=g*4+j, col q=r16
        }
        __builtin_amdgcn_s_setprio(0);
        const int qg = q0w + qs * 16 + r16;
        if (needmask) {
#pragma unroll
          for (int ks = 0; ks < 4; ++ks)
#pragma unroll
            for (int j = 0; j < 4; ++j)
              if (k0 + ks * 16 + g * 4 + j > qg) st[ks][j] = -__builtin_inff();
        }
        // fixed-shift softmax: p = exp2(s*CEXP - M32C); exact after final /l
        float ps = 0.f;
#pragma unroll
        for (int ks = 0; ks < 4; ++ks) {
          float p0 = exp2f(fmaf(st[ks][0], CEXP, -M32C));
          float p1 = exp2f(fmaf(st[ks][1], CEXP, -M32C));
          float p2 = exp2f(fmaf(st[ks][2], CEXP, -M32C));
          float p3 = exp2f(fmaf(st[ks][3], CEXP, -M32C));
          ps += (p0 + p1) + (p2 + p3);
          *(uint2*)&Ps[w][r16 * 64 + ((ks * 16 + g * 4) ^ swz)] =
              make_uint2(cvtpk(p0, p1), cvtpk(p2, p3));
        }
        lsum[qs] += ps;
        // PV for this q-subtile
        __builtin_amdgcn_s_setprio(1);
#pragma unroll
        for (int ks2 = 0; ks2 < 2; ++ks2) {
          bf16x8 pf =
              *(const bf16x8*)&Ps[w][r16 * 64 + ((ks2 * 32 + g * 8) ^ swz)];
#pragma unroll
          for (int dt = 0; dt < 4; ++dt)
            oacc[qs][dt] = __builtin_amdgcn_mfma_f32_16x16x32_bf16(
                pf, vfc[ks2][dt], oacc[qs][dt], 0, 0, 0);
        }
        __builtin_amdgcn_s_setprio(0);
      }
    }
    __syncthreads();
    cur ^= 1;
  }

#pragma unroll
  for (int qs = 0; qs < 2; ++qs) {
    float l = lsum[qs];
    l += __shfl_xor(l, 16);
    l += __shfl_xor(l, 32);
    float inv = 1.f / l;
    float iv[4];
#pragma unroll
    for (int j = 0; j < 4; ++j) iv[j] = __shfl(inv, g * 4 + j);
#pragma unroll
    for (int dt = 0; dt < 4; ++dt)
#pragma unroll
      for (int j = 0; j < 4; ++j) {
        size_t o = (size_t)(b * S_LEN + q0w + qs * 16 + g * 4 + j) * 2048 +
                   h * 64 + dt * 16 + r16;
        aout[o] = f2bf(oacc[qs][dt][j] * iv[j]);
      }
  }
}

extern "C" void kernel_launch(void* const* d_in, const int* in_sizes, int n_in,
                              void* d_out, int out_size, void* d_ws,
                              size_t ws_size, hipStream_t stream) {
  const float* x = (const float*)d_in[0];
  const float* fc = (const float*)d_in[1];
  const float* fs = (const float*)d_in[2];
  const float* wq = (const float*)d_in[3];
  const float* wk = (const float*)d_in[4];
  const float* wv = (const float*)d_in[5];
  const float* wo = (const float*)d_in[6];
  float* out = (float*)d_out;

  char* ws = (char*)d_ws;
  u16* xb = (u16*)(ws);
  u16* wqkvb = (u16*)(ws + 16777216);
  u16* wob = (u16*)(ws + 29360128);
  u16* qkvb = (u16*)(ws + 37748736);
  u16* vtb = (u16*)(ws + 62914560);
  u16* aoutb = (u16*)(ws + 67108864);

  cast_all<<<18432, 256, 0, stream>>>(x, wq, wk, wv, wo, xb, wqkvb, wob);

  // QKV = xb * wqkv^T with fused RoPE (Q,K tiles) + fused V-transpose (V tiles)
  gemm_bt2<128, 128, 2, 4, 1, 1><<<768, 512, 0, stream>>>(
      xb, wqkvb, qkvb, 2048, 3072, 24, fc, fs, vtb);
  attn_fwd<<<dim3(64, 8), 512, 0, stream>>>(qkvb, vtb, aoutb);
  gemm_bt2<128, 128, 2, 4, 0, 0><<<512, 512, 0, stream>>>(
      aoutb, wob, out, 2048, 2048, 16, nullptr, nullptr, nullptr);
}

// Round 16
// 170.723 us; speedup vs baseline: 1.4039x; 1.1199x over previous
//
#include <hip/hip_runtime.h>

typedef unsigned short u16;
typedef unsigned int u32;
typedef __attribute__((ext_vector_type(8))) short bf16x8;  // 8 bf16 (4 VGPRs)
typedef __attribute__((ext_vector_type(4))) float f32x4;

#define S_LEN 2048
#define QKV_N 3072  // 2048 Q + 512 K + 512 V
#define CEXP 0.18033688011f   // 0.125 * log2(e)
#define M32C 5.77078016f      // 32 * CEXP (fixed softmax shift, raw-score units)

__device__ __forceinline__ u16 f2bf(float f) {
  u32 u = __builtin_bit_cast(u32, f);
  u32 r = (u + 0x7FFFu + ((u >> 16) & 1u)) >> 16;  // RNE
  return (u16)r;
}
// one-instruction pack: u32 = bf16(hi)<<16 | bf16(lo), RNE
__device__ __forceinline__ u32 cvtpk(float lo, float hi) {
  u32 r;
  asm("v_cvt_pk_bf16_f32 %0, %1, %2" : "=v"(r) : "v"(lo), "v"(hi));
  return r;
}
__device__ __forceinline__ void gload16(const void* g, void* l) {
  __builtin_amdgcn_global_load_lds(
      (const __attribute__((address_space(1))) u32*)g,
      (__attribute__((address_space(3))) u32*)l, 16, 0, 0);
}

// ---------- fused cast f32 -> bf16 for all 5 inputs, 4 elems/thread ----------
__global__ void cast_all(const float* __restrict__ x, const float* __restrict__ wq,
                         const float* __restrict__ wk, const float* __restrict__ wv,
                         const float* __restrict__ wo, u16* __restrict__ xb,
                         u16* __restrict__ wqkvb, u16* __restrict__ wob) {
  int i = blockIdx.x * 256 + threadIdx.x;
  const float* s;
  u16* d;
  int so, dofs;
  if (i < 2097152) {
    s = x; d = xb; so = i; dofs = i;
  } else if (i < 3145728) {
    s = wq; d = wqkvb; so = i - 2097152; dofs = so;
  } else if (i < 3407872) {
    s = wk; d = wqkvb; so = i - 3145728; dofs = so + 1048576;
  } else if (i < 3670016) {
    s = wv; d = wqkvb; so = i - 3407872; dofs = so + 1310720;
  } else {
    s = wo; d = wob; so = i - 3670016; dofs = so;
  }
  float4 v = ((const float4*)s)[so];
  ((uint2*)d)[dofs] = make_uint2(cvtpk(v.x, v.y), cvtpk(v.z, v.w));
}

// ---------- NT GEMM v5: 128x128 tiles, 8 waves, dbuf, swizzle, 4-phase --------
// ROPE instance (gemm1): Q,K tiles (n0<2560) get RoPE'd into qkvb;
// V tiles (n0>=2560) are written TRANSPOSED to vt as
// vt[((b*8+kv)*64+d)*2048 + s] with packed 8B stores.
template <int BM, int BN, int WM, int WN, int OUT_BF16, int ROPE>
__global__ __launch_bounds__(512, 2) void gemm_bt2(const u16* __restrict__ A,
                                                   const u16* __restrict__ B,
                                                   void* __restrict__ Cv,
                                                   int K, int ldc, int nbx,
                                                   const float* __restrict__ fc,
                                                   const float* __restrict__ fs,
                                                   u16* __restrict__ vt) {
  constexpr int MR = BM / WM / 16;
  constexpr int NR = BN / WN / 16;
  constexpr int MR2 = MR / 2, NR2 = NR / 2;
  constexpr int AR = BM / 64, BR = BN / 64;
  __shared__ u16 As0[BM * 64], As1[BM * 64];
  __shared__ u16 Bs0[BN * 64], Bs1[BN * 64];

  const int tid = threadIdx.x;
  const int lane = tid & 63, w = tid >> 6;
  const int wm = w / WN, wn = w % WN;
  const int g = lane >> 4, r16 = lane & 15;
  const int swz = r16 & 7;

  const int nwg = gridDim.x;
  const int q = nwg >> 3, r = nwg & 7;
  const int xcd = blockIdx.x & 7, off = blockIdx.x >> 3;
  const int wg = (xcd < r ? xcd * (q + 1) : r * (q + 1) + (xcd - r) * q) + off;
  const int m0 = (wg / nbx) * BM, n0 = (wg % nbx) * BN;

  const int rowi = tid >> 3;
  const int scol = ((tid & 7) ^ (rowi & 7)) * 8;
  const u16* Ag0 = A + (size_t)(m0 + rowi) * K + scol;
  const u16* Bg0 = B + (size_t)(n0 + rowi) * K + scol;

  f32x4 acc[MR][NR];
#pragma unroll
  for (int mi = 0; mi < MR; ++mi)
#pragma unroll
    for (int ni = 0; ni < NR; ++ni) acc[mi][ni] = f32x4{0.f, 0.f, 0.f, 0.f};

  auto stage = [&](int kb, u16* Ad, u16* Bd) {
#pragma unroll
    for (int rr = 0; rr < AR; ++rr)
      gload16(Ag0 + (size_t)rr * 64 * K + kb, Ad + rr * 4096 + tid * 8);
#pragma unroll
    for (int rr = 0; rr < BR; ++rr)
      gload16(Bg0 + (size_t)rr * 64 * K + kb, Bd + rr * 4096 + tid * 8);
  };

  auto compute = [&](const u16* Asrc, const u16* Bsrc) {
    bf16x8 ac[MR2][2], bc[NR][2];
    const u16* Aw = Asrc + (wm * MR * 16 + r16) * 64;
    const u16* Bw = Bsrc + (wn * NR * 16 + r16) * 64;
#pragma unroll
    for (int mi = 0; mi < MR2; ++mi)
#pragma unroll
      for (int kk = 0; kk < 2; ++kk)
        ac[mi][kk] = *(const bf16x8*)(Aw + mi * 1024 + ((kk * 4 + g) ^ swz) * 8);
#pragma unroll
    for (int ni = 0; ni < NR2; ++ni)
#pragma unroll
      for (int kk = 0; kk < 2; ++kk)
        bc[ni][kk] = *(const bf16x8*)(Bw + ni * 1024 + ((kk * 4 + g) ^ swz) * 8);
    __builtin_amdgcn_s_setprio(1);
#pragma unroll
    for (int mi = 0; mi < MR2; ++mi)
#pragma unroll
      for (int ni = 0; ni < NR2; ++ni)
#pragma unroll
        for (int kk = 0; kk < 2; ++kk)
          acc[mi][ni] = __builtin_amdgcn_mfma_f32_16x16x32_bf16(
              ac[mi][kk], bc[ni][kk], acc[mi][ni], 0, 0, 0);
    __builtin_amdgcn_s_setprio(0);
#pragma unroll
    for (int ni = NR2; ni < NR; ++ni)
#pragma unroll
      for (int kk = 0; kk < 2; ++kk)
        bc[ni][kk] = *(const bf16x8*)(Bw + ni * 1024 + ((kk * 4 + g) ^ swz) * 8);
    __builtin_amdgcn_s_setprio(1);
#pragma unroll
    for (int mi = 0; mi < MR2; ++mi)
#pragma unroll
      for (int ni = NR2; ni < NR; ++ni)
#pragma unroll
        for (int kk = 0; kk < 2; ++kk)
          acc[mi][ni] = __builtin_amdgcn_mfma_f32_16x16x32_bf16(
              ac[mi][kk], bc[ni][kk], acc[mi][ni], 0, 0, 0);
    __builtin_amdgcn_s_setprio(0);
#pragma unroll
    for (int mi = 0; mi < MR2; ++mi)
#pragma unroll
      for (int kk = 0; kk < 2; ++kk)
        ac[mi][kk] =
            *(const bf16x8*)(Aw + (MR2 + mi) * 1024 + ((kk * 4 + g) ^ swz) * 8);
    __builtin_amdgcn_s_setprio(1);
#pragma unroll
    for (int mi = 0; mi < MR2; ++mi)
#pragma unroll
      for (int ni = NR2; ni < NR; ++ni)
#pragma unroll
        for (int kk = 0; kk < 2; ++kk)
          acc[MR2 + mi][ni] = __builtin_amdgcn_mfma_f32_16x16x32_bf16(
              ac[mi][kk], bc[ni][kk], acc[MR2 + mi][ni], 0, 0, 0);
    __builtin_amdgcn_s_setprio(0);
    __builtin_amdgcn_s_setprio(1);
#pragma unroll
    for (int mi = 0; mi < MR2; ++mi)
#pragma unroll
      for (int ni = 0; ni < NR2; ++ni)
#pragma unroll
        for (int kk = 0; kk < 2; ++kk)
          acc[MR2 + mi][ni] = __builtin_amdgcn_mfma_f32_16x16x32_bf16(
              ac[mi][kk], bc[ni][kk], acc[MR2 + mi][ni], 0, 0, 0);
    __builtin_amdgcn_s_setprio(0);
  };

  const int NT = K >> 6;
  stage(0, As0, Bs0);
  __syncthreads();
  for (int t = 0; t < NT; t += 2) {
    if (t + 1 < NT) stage((t + 1) * 64, As1, Bs1);
    compute(As0, Bs0);
    __syncthreads();
    if (t + 2 < NT) stage((t + 2) * 64, As0, Bs0);
    compute(As1, Bs1);
    __syncthreads();
  }

  if (ROPE && n0 >= 2560) {
#pragma unroll
    for (int mi = 0; mi < MR; ++mi)
#pragma unroll
      for (int ni = 0; ni < NR; ++ni) {
        int row = m0 + wm * MR * 16 + mi * 16 + g * 4;
        int col = n0 + wn * NR * 16 + ni * 16 + r16;
        int kv = (col - 2560) >> 6;
        int d = (col - 2560) & 63;
        int b_ = row >> 11, s0 = row & 2047;
        *(uint2*)&vt[(size_t)((b_ * 8 + kv) * 64 + d) * 2048 + s0] =
            make_uint2(cvtpk(acc[mi][ni][0], acc[mi][ni][1]),
                       cvtpk(acc[mi][ni][2], acc[mi][ni][3]));
      }
    return;
  }

#pragma unroll
  for (int mi = 0; mi < MR; ++mi)
#pragma unroll
    for (int ni = 0; ni < NR; ++ni) {
      int row = m0 + wm * MR * 16 + mi * 16 + g * 4;
      int col = n0 + wn * NR * 16 + ni * 16 + r16;
#pragma unroll
      for (int j = 0; j < 4; ++j) {
        float v = acc[mi][ni][j];
        if (ROPE) {
          float pv = __shfl_xor(v, 1);  // partner column of the RoPE pair
          int s = (row + j) & (S_LEN - 1);
          int fi = (col >> 1) & 31;
          float c = fc[s * 32 + fi], sn = fs[s * 32 + fi];
          v = fmaf(pv, (r16 & 1) ? sn : -sn, v * c);
        }
        if (OUT_BF16)
          ((u16*)Cv)[(size_t)(row + j) * ldc + col] = f2bf(v);
        else
          ((float*)Cv)[(size_t)(row + j) * ldc + col] = v;
      }
    }
}

// ---------- flash attention (known-good): dbuf KV, CU-balanced perm ----------
// grid (bh=64, y=16); 4 waves/block, 32 q/wave, KVBLK=64, dbuf LDS (40KB).
__global__ __launch_bounds__(256, 3) void attn_fwd(const u16* __restrict__ qkv,
                                                   const u16* __restrict__ vt,
                                                   u16* __restrict__ aout) {
  __shared__ u16 Ks[2][64 * 64];
  __shared__ u16 Vs[2][64 * 64];
  __shared__ u16 Ps[4][16 * 64];  // per-wave P tile, one 16-q subtile at a time

  const int bh = blockIdx.x;
  const int y = blockIdx.y;
  const int qt = (y < 4) ? (15 - y) : (y < 8) ? (y - 4) : (y < 12) ? y : (19 - y);
  const int b = bh >> 5, h = bh & 31, kvh = h >> 2;
  const int tid = threadIdx.x;
  const int w = tid >> 6, lane = tid & 63;
  const int g = lane >> 4, r16 = lane & 15;
  const int q0w = qt * 128 + w * 32;

  const u16* kbase = qkv + (size_t)b * S_LEN * QKV_N + 2048 + kvh * 64;
  const u16* vbase = vt + (size_t)(b * 8 + kvh) * 64 * S_LEN;

  const int srow = lane >> 3;
  const int scol = ((lane & 7) * 8) ^ (srow * 8);  // pre-swizzled source col
  const int swz = (r16 & 7) * 8;                   // read-side XOR (u16)

  bf16x8 qf[2][2];
#pragma unroll
  for (int qs = 0; qs < 2; ++qs) {
    const u16* qrow =
        qkv + (size_t)(b * S_LEN + q0w + qs * 16 + r16) * QKV_N + h * 64;
#pragma unroll
    for (int dh = 0; dh < 2; ++dh)
      qf[qs][dh] = *(const bf16x8*)(qrow + dh * 32 + g * 8);
  }

  f32x4 oacc[2][4];
#pragma unroll
  for (int qs = 0; qs < 2; ++qs)
#pragma unroll
    for (int dt = 0; dt < 4; ++dt) oacc[qs][dt] = f32x4{0.f, 0.f, 0.f, 0.f};
  float lsum[2] = {0.f, 0.f};

  const int nt = qt * 2 + 2;               // block k-tiles (64 keys each)
  const int ntw = ((q0w + 31) >> 6) + 1;   // this wave's causal tile count

#pragma unroll
  for (int c2 = 0; c2 < 2; ++c2) {
    int c = w * 2 + c2;
    gload16(kbase + (size_t)(c * 8 + srow) * QKV_N + scol, &Ks[0][c * 512]);
    gload16(vbase + (size_t)(c * 8 + srow) * 2048 + scol, &Vs[0][c * 512]);
  }
  __syncthreads();

  int cur = 0;
  for (int t = 0; t < nt; ++t) {
    if (t + 1 < nt) {
      int kk0 = (t + 1) * 64;
#pragma unroll
      for (int c2 = 0; c2 < 2; ++c2) {
        int c = w * 2 + c2;
        gload16(kbase + (size_t)(kk0 + c * 8 + srow) * QKV_N + scol,
                &Ks[cur ^ 1][c * 512]);
        gload16(vbase + (size_t)(c * 8 + srow) * 2048 + kk0 + scol,
                &Vs[cur ^ 1][c * 512]);
      }
    }
    if (t < ntw) {
      const int k0 = t * 64;
      bf16x8 kf[4][2];
#pragma unroll
      for (int ks = 0; ks < 4; ++ks)
#pragma unroll
        for (int dh = 0; dh < 2; ++dh)
          kf[ks][dh] = *(const bf16x8*)&Ks[cur][(ks * 16 + r16) * 64 +
                                               ((dh * 32 + g * 8) ^ swz)];
      bf16x8 vfc[2][4];  // V fragments cached in regs, shared across qs
#pragma unroll
      for (int ks2 = 0; ks2 < 2; ++ks2)
#pragma unroll
        for (int dt = 0; dt < 4; ++dt)
          vfc[ks2][dt] = *(const bf16x8*)&Vs[cur][(dt * 16 + r16) * 64 +
                                                  ((ks2 * 32 + g * 8) ^ swz)];
      const bool needmask = (k0 + 63 > q0w);
#pragma unroll
      for (int qs = 0; qs < 2; ++qs) {
        f32x4 st[4];
        __builtin_amdgcn_s_setprio(1);
#pragma unroll
        for (int ks = 0; ks < 4; ++ks) {
          f32x4 a = f32x4{0.f, 0.f, 0.f, 0.f};
          a = __builtin_amdgcn_mfma_f32_16x16x32_bf16(kf[ks][0], qf[qs][0], a, 0, 0, 0);
          a = __builtin_amdgcn_mfma_f32_16x16x32_bf16(kf[ks][1], qf[qs][1], a, 0, 0, 0);
          st[ks] = a;  // row k'=g*4+j, col q=r16
        }
        __builtin_amdgcn_s_setprio(0);
        const int qg = q0w + qs * 16 + r16;
        if (needmask) {
#pragma unroll
          for (int ks = 0; ks < 4; ++ks)
#pragma unroll
            for (int j = 0; j < 4; ++j)
              if (k0 + ks * 16 + g * 4 + j > qg) st[ks][j] = -__builtin_inff();
        }
        // fixed-shift softmax: p = exp2(s*CEXP - M32C); exact after final /l
        float ps = 0.f;
#pragma unroll
        for (int ks = 0; ks < 4; ++ks) {
          float p0 = exp2f(fmaf(st[ks][0], CEXP, -M32C));
          float p1 = exp2f(fmaf(st[ks][1], CEXP, -M32C));
          float p2 = exp2f(fmaf(st[ks][2], CEXP, -M32C));
          float p3 = exp2f(fmaf(st[ks][3], CEXP, -M32C));
          ps += (p0 + p1) + (p2 + p3);
          *(uint2*)&Ps[w][r16 * 64 + ((ks * 16 + g * 4) ^ swz)] =
              make_uint2(cvtpk(p0, p1), cvtpk(p2, p3));
        }
        lsum[qs] += ps;
        // PV for this q-subtile
        __builtin_amdgcn_s_setprio(1);
#pragma unroll
        for (int ks2 = 0; ks2 < 2; ++ks2) {
          bf16x8 pf =
              *(const bf16x8*)&Ps[w][r16 * 64 + ((ks2 * 32 + g * 8) ^ swz)];
#pragma unroll
          for (int dt = 0; dt < 4; ++dt)
            oacc[qs][dt] = __builtin_amdgcn_mfma_f32_16x16x32_bf16(
                pf, vfc[ks2][dt], oacc[qs][dt], 0, 0, 0);
        }
        __builtin_amdgcn_s_setprio(0);
      }
    }
    __syncthreads();
    cur ^= 1;
  }

#pragma unroll
  for (int qs = 0; qs < 2; ++qs) {
    float l = lsum[qs];
    l += __shfl_xor(l, 16);
    l += __shfl_xor(l, 32);
    float inv = 1.f / l;
    float iv[4];
#pragma unroll
    for (int j = 0; j < 4; ++j) iv[j] = __shfl(inv, g * 4 + j);
#pragma unroll
    for (int dt = 0; dt < 4; ++dt)
#pragma unroll
      for (int j = 0; j < 4; ++j) {
        size_t o = (size_t)(b * S_LEN + q0w + qs * 16 + g * 4 + j) * 2048 +
                   h * 64 + dt * 16 + r16;
        aout[o] = f2bf(oacc[qs][dt][j] * iv[j]);
      }
  }
}

extern "C" void kernel_launch(void* const* d_in, const int* in_sizes, int n_in,
                              void* d_out, int out_size, void* d_ws,
                              size_t ws_size, hipStream_t stream) {
  const float* x = (const float*)d_in[0];
  const float* fc = (const float*)d_in[1];
  const float* fs = (const float*)d_in[2];
  const float* wq = (const float*)d_in[3];
  const float* wk = (const float*)d_in[4];
  const float* wv = (const float*)d_in[5];
  const float* wo = (const float*)d_in[6];
  float* out = (float*)d_out;

  char* ws = (char*)d_ws;
  u16* xb = (u16*)(ws);
  u16* wqkvb = (u16*)(ws + 16777216);
  u16* wob = (u16*)(ws + 29360128);
  u16* qkvb = (u16*)(ws + 37748736);
  u16* vtb = (u16*)(ws + 62914560);
  u16* aoutb = (u16*)(ws + 67108864);

  cast_all<<<18432, 256, 0, stream>>>(x, wq, wk, wv, wo, xb, wqkvb, wob);

  // QKV = xb * wqkv^T with fused RoPE (Q,K tiles) + fused V-transpose (V tiles)
  // 128x128 tiles: grid 32x24 = 768 blocks (2 resident/CU)
  gemm_bt2<128, 128, 2, 4, 1, 1><<<768, 512, 0, stream>>>(
      xb, wqkvb, qkvb, 2048, 3072, 24, fc, fs, vtb);
  attn_fwd<<<dim3(64, 16), 256, 0, stream>>>(qkvb, vtb, aoutb);
  // out = aout * wo^T: 128x128 tiles, grid 32x16 = 512 blocks (2/CU)
  gemm_bt2<128, 128, 2, 4, 0, 0><<<512, 512, 0, stream>>>(
      aoutb, wob, out, 2048, 2048, 16, nullptr, nullptr, nullptr);
}